// Round 1
// baseline (3714.691 us; speedup 1.0000x reference)
//
#include <hip/hip_runtime.h>
#include <hip/hip_bf16.h>

// Problem constants (from reference)
#define N0 1000000
#define N1 102400
#define N2 10240
#define N3 1024
#define E0 1024000
#define E1 102400
#define E2 10240
#define D_IN 128
#define D_H 256
#define D_OUT 40

// ---------------- zero kernel (grid-stride float4) ----------------
__global__ void zero_kernel(float4* __restrict__ p, long long n4) {
    long long i = (long long)blockIdx.x * blockDim.x + threadIdx.x;
    long long stride = (long long)gridDim.x * blockDim.x;
    float4 z = make_float4(0.f, 0.f, 0.f, 0.f);
    for (; i < n4; i += stride) p[i] = z;
}

// ---------------- scatter: aggr[dst[e]] += h[src[e]]; cnt[dst[e]] += 1 -----
template<int D>
__global__ __launch_bounds__(256)
void scatter_accum(const float* __restrict__ h,
                   const int* __restrict__ src,
                   const int* __restrict__ dst,
                   float* __restrict__ aggr,
                   float* __restrict__ cnt,
                   int E)
{
    constexpr int DV = D / 4;  // float4 chunks per row
    long long gid = (long long)blockIdx.x * blockDim.x + threadIdx.x;
    if (gid >= (long long)E * DV) return;
    int e  = (int)(gid / DV);
    int kv = (int)(gid % DV);
    int s = src[e], d = dst[e];
    const float4 v = *(const float4*)(h + (size_t)s * D + kv * 4);
    float* ap = aggr + (size_t)d * D + kv * 4;
    atomicAdd(ap + 0, v.x);
    atomicAdd(ap + 1, v.y);
    atomicAdd(ap + 2, v.z);
    atomicAdd(ap + 3, v.w);
    if (kv == 0) atomicAdd(cnt + d, 1.0f);
}

// ---------------- fused SAGE GEMM ----------------
// out[i][j] = act( (aggr[i]/max(cnt[i],1)) . Wl[:,j] + bias[j] + htgt[i] . Wr[:,j] )
// Treated as [A_scaled | htgt] (M x 2K) @ [[Wl],[Wr]] (2K x N).
#define TILE 64
#define BKK 32

template<bool RELU>
__global__ __launch_bounds__(256)
void sage_gemm(const float* __restrict__ aggr,
               const float* __restrict__ cnt,
               const float* __restrict__ htgt,
               const float* __restrict__ Wl,
               const float* __restrict__ Wr,
               const float* __restrict__ bias,
               float* __restrict__ out,
               int M, int N, int K)  // K per-matrix; total 2K
{
    __shared__ float As[BKK][TILE + 1];
    __shared__ float Bs[BKK][TILE + 1];
    __shared__ float ic[TILE];

    int tid = threadIdx.x;
    int row0 = blockIdx.y * TILE;
    int col0 = blockIdx.x * TILE;

    if (tid < TILE) {
        int r = row0 + tid;
        float c = (r < M) ? cnt[r] : 1.0f;
        ic[tid] = 1.0f / fmaxf(c, 1.0f);
    }
    __syncthreads();

    float acc[4][4] = {};
    int tx = tid & 15, ty = tid >> 4;  // 16 x 16 thread grid

    int K2 = 2 * K;
    for (int k0 = 0; k0 < K2; k0 += BKK) {
        // A tile: TILE rows x BKK k
        #pragma unroll
        for (int l = 0; l < (TILE * BKK) / 256; ++l) {
            int idx = l * 256 + tid;
            int kk = idx & (BKK - 1);
            int i  = idx / BKK;
            int kg = k0 + kk;
            int ig = row0 + i;
            float v = 0.f;
            if (ig < M) {
                if (kg < K) v = aggr[(size_t)ig * K + kg] * ic[i];
                else        v = htgt[(size_t)ig * K + (kg - K)];
            }
            As[kk][i] = v;
        }
        // B tile: BKK k x TILE cols
        #pragma unroll
        for (int l = 0; l < (TILE * BKK) / 256; ++l) {
            int idx = l * 256 + tid;
            int j  = idx & (TILE - 1);
            int kk = idx / TILE;
            int kg = k0 + kk;
            int jg = col0 + j;
            float v = 0.f;
            if (jg < N) {
                if (kg < K) v = Wl[(size_t)kg * N + jg];
                else        v = Wr[(size_t)(kg - K) * N + jg];
            }
            Bs[kk][j] = v;
        }
        __syncthreads();

        #pragma unroll
        for (int kk = 0; kk < BKK; ++kk) {
            float a[4], b[4];
            #pragma unroll
            for (int m = 0; m < 4; ++m) a[m] = As[kk][ty + m * 16];
            #pragma unroll
            for (int n = 0; n < 4; ++n) b[n] = Bs[kk][tx + n * 16];
            #pragma unroll
            for (int m = 0; m < 4; ++m)
                #pragma unroll
                for (int n = 0; n < 4; ++n)
                    acc[m][n] += a[m] * b[n];
        }
        __syncthreads();
    }

    #pragma unroll
    for (int m = 0; m < 4; ++m) {
        int ig = row0 + ty + m * 16;
        if (ig >= M) continue;
        #pragma unroll
        for (int n = 0; n < 4; ++n) {
            int jg = col0 + tx + n * 16;
            if (jg >= N) continue;
            float v = acc[m][n] + bias[jg];
            if (RELU) v = fmaxf(v, 0.f);
            out[(size_t)ig * N + jg] = v;
        }
    }
}

// ---------------- log_softmax over rows of (M x N), N <= 64 ----------------
__global__ __launch_bounds__(256)
void log_softmax_kernel(float* __restrict__ out, int M, int N) {
    int row = blockIdx.x * (blockDim.x >> 6) + (threadIdx.x >> 6);
    int lane = threadIdx.x & 63;
    if (row >= M) return;
    float v = (lane < N) ? out[(size_t)row * N + lane] : -INFINITY;
    float m = v;
    #pragma unroll
    for (int off = 32; off; off >>= 1) m = fmaxf(m, __shfl_xor(m, off, 64));
    float e = (lane < N) ? expf(v - m) : 0.f;
    float s = e;
    #pragma unroll
    for (int off = 32; off; off >>= 1) s += __shfl_xor(s, off, 64);
    if (lane < N) out[(size_t)row * N + lane] = v - m - logf(s);
}

extern "C" void kernel_launch(void* const* d_in, const int* in_sizes, int n_in,
                              void* d_out, int out_size, void* d_ws, size_t ws_size,
                              hipStream_t stream) {
    const float* x    = (const float*)d_in[0];
    const int*   src0 = (const int*)d_in[1];
    const int*   dst0 = (const int*)d_in[2];
    const int*   src1 = (const int*)d_in[3];
    const int*   dst1 = (const int*)d_in[4];
    const int*   src2 = (const int*)d_in[5];
    const int*   dst2 = (const int*)d_in[6];
    const float* Wl0  = (const float*)d_in[7];
    const float* bl0  = (const float*)d_in[8];
    const float* Wr0  = (const float*)d_in[9];
    const float* Wl1  = (const float*)d_in[10];
    const float* bl1  = (const float*)d_in[11];
    const float* Wr1  = (const float*)d_in[12];
    const float* Wl2  = (const float*)d_in[13];
    const float* bl2  = (const float*)d_in[14];
    const float* Wr2  = (const float*)d_in[15];
    float* out = (float*)d_out;
    float* f   = (float*)d_ws;

    // Workspace layout (floats):
    //  [0, N1)                cnt0
    //  [N1, N1*129)           aggr0 (N1 x 128)
    //  [N1*129, N1*385)       h1    (N1 x 256)
    // Layer-1/2 buffers reuse the cnt0/aggr0 region (dead after gemm0):
    //  [0, N2)                cnt1
    //  [N2, N2*257)           aggr1 (N2 x 256)
    //  [N2*257, N2*513)       h2    (N2 x 256)
    //  [N2*513, N2*513+N3)    cnt2
    //  [.., +N3*256)          aggr2 (N3 x 256)
    float* cnt0  = f;
    float* aggr0 = f + (size_t)N1;
    float* h1    = f + (size_t)N1 * 129;
    float* cnt1  = f;
    float* aggr1 = f + (size_t)N2;
    float* h2    = f + (size_t)N2 * 257;
    float* cnt2  = h2 + (size_t)N2 * 256;
    float* aggr2 = cnt2 + (size_t)N3;

    // ---- Layer 0 ----
    zero_kernel<<<2048, 256, 0, stream>>>((float4*)cnt0, (long long)N1 * 129 / 4);
    {
        long long total = (long long)E0 * (D_IN / 4);
        int blocks = (int)((total + 255) / 256);
        scatter_accum<D_IN><<<blocks, 256, 0, stream>>>(x, src0, dst0, aggr0, cnt0, E0);
    }
    sage_gemm<true><<<dim3(D_H / TILE, N1 / TILE), 256, 0, stream>>>(
        aggr0, cnt0, x, Wl0, Wr0, bl0, h1, N1, D_H, D_IN);

    // ---- Layer 1 ----
    zero_kernel<<<1024, 256, 0, stream>>>((float4*)cnt1, (long long)N2 * 257 / 4);
    {
        long long total = (long long)E1 * (D_H / 4);
        int blocks = (int)((total + 255) / 256);
        scatter_accum<D_H><<<blocks, 256, 0, stream>>>(h1, src1, dst1, aggr1, cnt1, E1);
    }
    sage_gemm<true><<<dim3(D_H / TILE, N2 / TILE), 256, 0, stream>>>(
        aggr1, cnt1, h1, Wl1, Wr1, bl1, h2, N2, D_H, D_H);

    // ---- Layer 2 ----
    zero_kernel<<<256, 256, 0, stream>>>((float4*)cnt2, (long long)N3 * 257 / 4);
    {
        long long total = (long long)E2 * (D_H / 4);
        int blocks = (int)((total + 255) / 256);
        scatter_accum<D_H><<<blocks, 256, 0, stream>>>(h2, src2, dst2, aggr2, cnt2, E2);
    }
    sage_gemm<false><<<dim3(1, N3 / TILE), 256, 0, stream>>>(
        aggr2, cnt2, h2, Wl2, Wr2, bl2, out, N3, D_OUT, D_H);

    // ---- log_softmax ----
    log_softmax_kernel<<<(N3 + 3) / 4, 256, 0, stream>>>(out, N3, D_OUT);
}

// Round 2
// 1626.268 us; speedup vs baseline: 2.2842x; 2.2842x over previous
//
#include <hip/hip_runtime.h>
#include <hip/hip_bf16.h>

// Problem constants (from reference)
#define N0 1000000
#define N1 102400
#define N2 10240
#define N3 1024
#define E0 1024000
#define E1 102400
#define E2 10240
#define D_IN 128
#define D_H 256
#define D_OUT 40

// ---------------- small utility kernels ----------------
__global__ void zero_ints(int* __restrict__ p, int n) {
    int i = blockIdx.x * blockDim.x + threadIdx.x;
    if (i < n) p[i] = 0;
}

__global__ void count_deg(const int* __restrict__ dst, int E, int* __restrict__ deg) {
    int e = blockIdx.x * blockDim.x + threadIdx.x;
    if (e < E) atomicAdd(&deg[dst[e]], 1);
}

// Block-level exclusive scan: each block covers 1024 elements (256 thr x 4).
// Writes local-exclusive scan into rs, block total into bsum[b].
__global__ __launch_bounds__(256)
void scan_blocks(const int* __restrict__ deg, int n,
                 int* __restrict__ rs, int* __restrict__ bsum) {
    __shared__ int s[256];
    int b = blockIdx.x, t = threadIdx.x;
    int base = b * 1024 + t * 4;
    int v[4]; int sum = 0;
    #pragma unroll
    for (int k = 0; k < 4; ++k) {
        int idx = base + k;
        v[k] = (idx < n) ? deg[idx] : 0;
        sum += v[k];
    }
    s[t] = sum; __syncthreads();
    for (int off = 1; off < 256; off <<= 1) {
        int x = (t >= off) ? s[t - off] : 0;
        __syncthreads();
        s[t] += x;
        __syncthreads();
    }
    int excl = s[t] - sum;  // exclusive prefix of this thread's chunk
    #pragma unroll
    for (int k = 0; k < 4; ++k) {
        int idx = base + k;
        if (idx < n) rs[idx] = excl;
        excl += v[k];
    }
    if (t == 255) bsum[b] = s[255];
}

// Exclusive scan of nb (<=256) block sums, in place.
__global__ __launch_bounds__(256)
void scan_top(int* __restrict__ bsum, int nb) {
    __shared__ int s[256];
    int t = threadIdx.x;
    int v = (t < nb) ? bsum[t] : 0;
    s[t] = v; __syncthreads();
    for (int off = 1; off < 256; off <<= 1) {
        int x = (t >= off) ? s[t - off] : 0;
        __syncthreads();
        s[t] += x;
        __syncthreads();
    }
    if (t < nb) bsum[t] = s[t] - v;  // exclusive
}

__global__ void add_offsets(int* __restrict__ rs, int n, const int* __restrict__ bsum) {
    int i = blockIdx.x * blockDim.x + threadIdx.x;
    if (i < n) rs[i] += bsum[i >> 10];
}

// Fill edge lists: pos = rs[dst]++ ; esrc[pos] = src.
// After this kernel, rs[i] == start of row i+1 (i.e. rs becomes "row end" array).
__global__ void fill_edges(const int* __restrict__ src, const int* __restrict__ dst,
                           int E, int* __restrict__ rs, int* __restrict__ esrc) {
    int e = blockIdx.x * blockDim.x + threadIdx.x;
    if (e < E) {
        int pos = atomicAdd(&rs[dst[e]], 1);
        esrc[pos] = src[e];
    }
}

// ---------------- gather + mean: one wave per destination row ----------------
// rs_after[i] = end of row i (= start of row i+1); start of row i = rs_after[i-1] (0 for i==0).
template<int D>
__global__ __launch_bounds__(256)
void gather_mean(const float* __restrict__ h, const int* __restrict__ rs_after,
                 const int* __restrict__ esrc, float* __restrict__ aggr, int M) {
    int row  = blockIdx.x * (blockDim.x >> 6) + (threadIdx.x >> 6);
    int lane = threadIdx.x & 63;
    if (row >= M) return;
    int start = (row == 0) ? 0 : rs_after[row - 1];
    int end   = rs_after[row];
    constexpr int F = D / 64;
    float acc[F] = {};
    int j = start;
    for (; j + 1 < end; j += 2) {
        int s0 = esrc[j], s1 = esrc[j + 1];
        const float* p0 = h + (size_t)s0 * D + lane;
        const float* p1 = h + (size_t)s1 * D + lane;
        #pragma unroll
        for (int f = 0; f < F; ++f) acc[f] += p0[f * 64] + p1[f * 64];
    }
    if (j < end) {
        int s0 = esrc[j];
        const float* p0 = h + (size_t)s0 * D + lane;
        #pragma unroll
        for (int f = 0; f < F; ++f) acc[f] += p0[f * 64];
    }
    float inv = 1.0f / fmaxf((float)(end - start), 1.0f);
    float* o = aggr + (size_t)row * D + lane;
    #pragma unroll
    for (int f = 0; f < F; ++f) o[f * 64] = acc[f] * inv;
}

// ---------------- fused SAGE GEMM ----------------
// out[i][j] = act( aggr[i] . Wl[:,j] + bias[j] + htgt[i] . Wr[:,j] )
// Treated as [aggr | htgt] (M x 2K) @ [[Wl],[Wr]] (2K x N). aggr is already the mean.
#define TILE 64
#define BKK 32

template<bool RELU>
__global__ __launch_bounds__(256)
void sage_gemm(const float* __restrict__ aggr,
               const float* __restrict__ htgt,
               const float* __restrict__ Wl,
               const float* __restrict__ Wr,
               const float* __restrict__ bias,
               float* __restrict__ out,
               int M, int N, int K)  // K per-matrix; total 2K
{
    __shared__ float As[BKK][TILE + 1];
    __shared__ float Bs[BKK][TILE + 1];

    int tid = threadIdx.x;
    int row0 = blockIdx.y * TILE;
    int col0 = blockIdx.x * TILE;

    float acc[4][4] = {};
    int tx = tid & 15, ty = tid >> 4;  // 16 x 16 thread grid

    int K2 = 2 * K;
    for (int k0 = 0; k0 < K2; k0 += BKK) {
        #pragma unroll
        for (int l = 0; l < (TILE * BKK) / 256; ++l) {
            int idx = l * 256 + tid;
            int kk = idx & (BKK - 1);
            int i  = idx / BKK;
            int kg = k0 + kk;
            int ig = row0 + i;
            float v = 0.f;
            if (ig < M) {
                if (kg < K) v = aggr[(size_t)ig * K + kg];
                else        v = htgt[(size_t)ig * K + (kg - K)];
            }
            As[kk][i] = v;
        }
        #pragma unroll
        for (int l = 0; l < (TILE * BKK) / 256; ++l) {
            int idx = l * 256 + tid;
            int j  = idx & (TILE - 1);
            int kk = idx / TILE;
            int kg = k0 + kk;
            int jg = col0 + j;
            float v = 0.f;
            if (jg < N) {
                if (kg < K) v = Wl[(size_t)kg * N + jg];
                else        v = Wr[(size_t)(kg - K) * N + jg];
            }
            Bs[kk][j] = v;
        }
        __syncthreads();

        #pragma unroll
        for (int kk = 0; kk < BKK; ++kk) {
            float a[4], b[4];
            #pragma unroll
            for (int m = 0; m < 4; ++m) a[m] = As[kk][ty + m * 16];
            #pragma unroll
            for (int n = 0; n < 4; ++n) b[n] = Bs[kk][tx + n * 16];
            #pragma unroll
            for (int m = 0; m < 4; ++m)
                #pragma unroll
                for (int n = 0; n < 4; ++n)
                    acc[m][n] += a[m] * b[n];
        }
        __syncthreads();
    }

    #pragma unroll
    for (int m = 0; m < 4; ++m) {
        int ig = row0 + ty + m * 16;
        if (ig >= M) continue;
        #pragma unroll
        for (int n = 0; n < 4; ++n) {
            int jg = col0 + tx + n * 16;
            if (jg >= N) continue;
            float v = acc[m][n] + bias[jg];
            if (RELU) v = fmaxf(v, 0.f);
            out[(size_t)ig * N + jg] = v;
        }
    }
}

// ---------------- log_softmax over rows of (M x N), N <= 64 ----------------
__global__ __launch_bounds__(256)
void log_softmax_kernel(float* __restrict__ out, int M, int N) {
    int row = blockIdx.x * (blockDim.x >> 6) + (threadIdx.x >> 6);
    int lane = threadIdx.x & 63;
    if (row >= M) return;
    float v = (lane < N) ? out[(size_t)row * N + lane] : -INFINITY;
    float m = v;
    #pragma unroll
    for (int off = 32; off; off >>= 1) m = fmaxf(m, __shfl_xor(m, off, 64));
    float e = (lane < N) ? expf(v - m) : 0.f;
    float s = e;
    #pragma unroll
    for (int off = 32; off; off >>= 1) s += __shfl_xor(s, off, 64);
    if (lane < N) out[(size_t)row * N + lane] = v - m - logf(s);
}

// ---------------- host-side orchestration ----------------
static void build_csr(const int* dst, int E, int n_tgt,
                      int* deg, int* rs, int* bsum, const int* src, int* esrc,
                      hipStream_t stream) {
    zero_ints<<<(n_tgt + 255) / 256, 256, 0, stream>>>(deg, n_tgt);
    count_deg<<<(E + 255) / 256, 256, 0, stream>>>(dst, E, deg);
    int nb = (n_tgt + 1023) / 1024;  // <= 100 for N1
    scan_blocks<<<nb, 256, 0, stream>>>(deg, n_tgt, rs, bsum);
    scan_top<<<1, 256, 0, stream>>>(bsum, nb);
    add_offsets<<<(n_tgt + 255) / 256, 256, 0, stream>>>(rs, n_tgt, bsum);
    fill_edges<<<(E + 255) / 256, 256, 0, stream>>>(src, dst, E, rs, esrc);
}

extern "C" void kernel_launch(void* const* d_in, const int* in_sizes, int n_in,
                              void* d_out, int out_size, void* d_ws, size_t ws_size,
                              hipStream_t stream) {
    const float* x    = (const float*)d_in[0];
    const int*   src0 = (const int*)d_in[1];
    const int*   dst0 = (const int*)d_in[2];
    const int*   src1 = (const int*)d_in[3];
    const int*   dst1 = (const int*)d_in[4];
    const int*   src2 = (const int*)d_in[5];
    const int*   dst2 = (const int*)d_in[6];
    const float* Wl0  = (const float*)d_in[7];
    const float* bl0  = (const float*)d_in[8];
    const float* Wr0  = (const float*)d_in[9];
    const float* Wl1  = (const float*)d_in[10];
    const float* bl1  = (const float*)d_in[11];
    const float* Wr1  = (const float*)d_in[12];
    const float* Wl2  = (const float*)d_in[13];
    const float* bl2  = (const float*)d_in[14];
    const float* Wr2  = (const float*)d_in[15];
    float* out = (float*)d_out;
    float* f   = (float*)d_ws;

    // Workspace layout (floats):
    //  [0, 13107200)            aggr0 (N1 x 128); region reused after gemm0 for:
    //       aggr1 [0, 2621440) | h2 [2621440, 5242880) | aggr2 [5242880, 5505024)
    //       esrc1 (E1 ints) at [5505024, ...) | esrc2 (E2 ints) after
    //  [13107200, 39321600)     h1 (N1 x 256); its head doubles as esrc0 (E0 ints)
    //                           BEFORE gemm0 writes h1 (stream-ordered, no overlap in time)
    //  [39321600, +2*N1+256)    int scratch: deg (N1) | rs (N1) | bsum (256)
    float* aggr0 = f;
    float* h1    = f + (size_t)13107200;
    int*   ib    = (int*)(f + (size_t)39321600);
    int* deg  = ib;
    int* rs   = ib + N1;
    int* bsum = ib + 2 * N1;
    int* esrc0 = (int*)h1;                       // alias: dead before gemm0 writes h1
    float* aggr1 = f;                            // after gemm0, aggr0 region is free
    float* h2    = f + (size_t)2621440;
    float* aggr2 = f + (size_t)5242880;
    int* esrc1 = (int*)(f + (size_t)5505024);
    int* esrc2 = (int*)(f + (size_t)5505024 + E1);

    // ---- Layer 0 ----
    build_csr(dst0, E0, N1, deg, rs, bsum, src0, esrc0, stream);
    gather_mean<D_IN><<<(N1 + 3) / 4, 256, 0, stream>>>(x, rs, esrc0, aggr0, N1);
    sage_gemm<true><<<dim3(D_H / TILE, N1 / TILE), 256, 0, stream>>>(
        aggr0, x, Wl0, Wr0, bl0, h1, N1, D_H, D_IN);

    // ---- Layer 1 ----  (CSR buffers live in the now-dead aggr0 region)
    build_csr(dst1, E1, N2, deg, rs, bsum, src1, esrc1, stream);
    gather_mean<D_H><<<(N2 + 3) / 4, 256, 0, stream>>>(h1, rs, esrc1, aggr1, N2);
    sage_gemm<true><<<dim3(D_H / TILE, N2 / TILE), 256, 0, stream>>>(
        aggr1, h1, Wl1, Wr1, bl1, h2, N2, D_H, D_H);

    // ---- Layer 2 ----
    build_csr(dst2, E2, N3, deg, rs, bsum, src2, esrc2, stream);
    gather_mean<D_H><<<(N3 + 3) / 4, 256, 0, stream>>>(h2, rs, esrc2, aggr2, N3);
    sage_gemm<false><<<dim3(1, N3 / TILE), 256, 0, stream>>>(
        aggr2, h2, Wl2, Wr2, bl2, out, N3, D_OUT, D_H);

    // ---- log_softmax ----
    log_softmax_kernel<<<(N3 + 3) / 4, 256, 0, stream>>>(out, N3, D_OUT);
}